// Round 1
// baseline (299.429 us; speedup 1.0000x reference)
//
#include <hip/hip_runtime.h>
#include <hip/hip_fp16.h>
#include <math.h>

#define B_ 4
#define S_ 8192
#define D_ 512
#define H_ 8
#define U_ 45            // int(5*ln(8193)) = 45
#define NCHUNK 16        // 512 keys per attention block

typedef unsigned short ushortT;
typedef __attribute__((ext_vector_type(8))) _Float16 half8;
typedef __attribute__((ext_vector_type(4))) float f32x4;

__device__ __forceinline__ ushortT f2h(float f) {
    return __half_as_ushort(__float2half(f));    // RNE
}
__device__ __forceinline__ float h2f(ushortT u) {
    return __half2float(__ushort_as_half(u));
}

__device__ __forceinline__ void gload_lds16(const ushortT* g, ushortT* l) {
    __builtin_amdgcn_global_load_lds(
        (const __attribute__((address_space(1))) void*)g,
        (__attribute__((address_space(3))) void*)l,
        16, 0, 0);
}

// ---------------------------------------------------------------------------
// Fused pre-pass: blocks [0,8192): X fp32 -> fp16 (block 0 zeroes vsum +
// outbase).  Blocks [8192, 8960): weight transpose+convert WT[n][k]=W[k][n].
// ---------------------------------------------------------------------------
__global__ __launch_bounds__(256) void prep_kernel(
    const float* __restrict__ X, ushortT* __restrict__ Xf,
    const float* __restrict__ Wq, const float* __restrict__ Wk,
    const float* __restrict__ Wv,
    ushortT* __restrict__ WqT, ushortT* __restrict__ WkT,
    ushortT* __restrict__ WvT,
    float* __restrict__ vsum, float* __restrict__ outbase)
{
    __shared__ float t[32][33];
    const int bx = blockIdx.x;
    if (bx < 8192) {
        if (bx == 0) {
            float4 z = {0.f, 0.f, 0.f, 0.f};
            *(float4*)&vsum[threadIdx.x * 8]        = z;
            *(float4*)&vsum[threadIdx.x * 8 + 4]    = z;
            *(float4*)&outbase[threadIdx.x * 8]     = z;
            *(float4*)&outbase[threadIdx.x * 8 + 4] = z;
        }
        size_t i = ((size_t)bx * 256 + threadIdx.x) * 8;
        float4 a = *(const float4*)(X + i);
        float4 b = *(const float4*)(X + i + 4);
        *(ushort4*)(Xf + i)     = make_ushort4(f2h(a.x), f2h(a.y), f2h(a.z), f2h(a.w));
        *(ushort4*)(Xf + i + 4) = make_ushort4(f2h(b.x), f2h(b.y), f2h(b.z), f2h(b.w));
    } else {
        const int idx = bx - 8192;
        const int z = idx >> 8, rem = idx & 255;
        const int r0 = (rem >> 4) * 32, c0 = (rem & 15) * 32;
        const float* W = (z == 0) ? Wq : (z == 1) ? Wk : Wv;
        ushortT* O = (z == 0) ? WqT : (z == 1) ? WkT : WvT;
        const int tx = threadIdx.x & 31, ty4 = (threadIdx.x >> 5) * 4;
#pragma unroll
        for (int i = 0; i < 4; ++i)
            t[ty4 + i][tx] = W[(size_t)(r0 + ty4 + i) * 512 + c0 + tx];
        __syncthreads();
#pragma unroll
        for (int i = 0; i < 4; ++i)
            O[(size_t)(c0 + ty4 + i) * 512 + r0 + tx] = f2h(t[tx][ty4 + i]);
    }
}

// ---------------------------------------------------------------------------
// MFMA QKV projection, fp16, BK=64, 3-pass.
// R10: double-buffered LDS (64KB) + 2-phase pipeline (T3 minimum recipe):
//   issue next K-tile's global_load_lds into buf^1 BEFORE computing buf,
//   single barrier per K-step (was 2).  The vmcnt(0) drain at the barrier
//   now waits for loads issued one full MFMA-phase earlier, so HBM latency
//   hides under the 32 MFMA + 16 ds_read of the current step.
// grid (256, 12): y 0-3 Q n-tiles, 4-7 K n-tiles, 8-11 V column-tiles.
// 128x128 tile, 4 waves 2x2, wave = 64x64.  8-chunk rotate swizzle: 0
// conflicts (verified SQ_LDS_BANK_CONFLICT=0).
// ---------------------------------------------------------------------------
__global__ __launch_bounds__(256, 2) void qkv_mfma(
    const ushortT* __restrict__ Xf,
    const ushortT* __restrict__ WqT, const ushortT* __restrict__ WkT,
    const ushortT* __restrict__ WvT,
    const float* __restrict__ bq, const float* __restrict__ bk,
    const float* __restrict__ bv,
    ushortT* __restrict__ Qbuf, ushortT* __restrict__ Kbuf,
    ushortT* __restrict__ VT,
    float* __restrict__ sparsity, float* __restrict__ vsum)
{
    __shared__ ushortT lds[4 * 128 * 64];   // [buf][A|B], 16KB quarters, 64KB

    const int tid  = threadIdx.x;
    const int w    = tid >> 6, lane = tid & 63;
    const int quad = lane >> 4, c16 = lane & 15;
    const int wr   = w >> 1,  wc  = w & 1;
    const int mat  = blockIdx.y >> 2;        // 0=Q 1=K 2=V
    const int nt   = blockIdx.y & 3;
    const int m0   = blockIdx.x * 128;
    const int n0   = nt * 128;

    const int srowL = lane >> 3;                            // 0..7 within wave
    const int slc   = (((lane & 7) - (srowL & 7)) & 7) * 8; // swizzled src chunk
    const int rrot  = c16 & 7;

    const ushortT* Ag = (mat == 2) ? WvT : Xf;
    const ushortT* Bg = (mat == 0) ? WqT : (mat == 1) ? WkT : Xf;
    const int arow0 = (mat == 2) ? n0 : m0;
    const int brow0 = (mat == 2) ? m0 : n0;

    f32x4 acc[4][4];
#pragma unroll
    for (int i = 0; i < 4; ++i)
#pragma unroll
        for (int j = 0; j < 4; ++j) acc[i][j] = (f32x4){0.f, 0.f, 0.f, 0.f};

    auto stage = [&](int k0, ushortT* dstA) {
        ushortT* dstB = dstA + 8192;
#pragma unroll
        for (int c = 0; c < 4; ++c) {
            const int R = c * 32 + w * 8 + srowL;
            const int lbase = c * 2048 + w * 512;          // halves
            gload_lds16(Ag + (size_t)(arow0 + R) * 512 + k0 + slc, dstA + lbase);
            gload_lds16(Bg + (size_t)(brow0 + R) * 512 + k0 + slc, dstB + lbase);
        }
    };

    // prologue: stage tile 0 into buf 0, drain, barrier
    stage(0, lds);
    __syncthreads();

#pragma unroll
    for (int t = 0; t < 8; ++t) {
        ushortT* As = lds + (t & 1) * 16384;
        const ushortT* Bs = As + 8192;
        if (t < 7) stage((t + 1) * 64, lds + ((t + 1) & 1) * 16384);
#pragma unroll
        for (int kk = 0; kk < 2; ++kk) {
            const int phk = (((kk * 4 + quad) + rrot) & 7) * 8;
            half8 af[4], bf[4];
#pragma unroll
            for (int i = 0; i < 4; ++i) {
                af[i] = *(const half8*)&As[(wr * 64 + i * 16 + c16) * 64 + phk];
                bf[i] = *(const half8*)&Bs[(wc * 64 + i * 16 + c16) * 64 + phk];
            }
#pragma unroll
            for (int i = 0; i < 4; ++i)
#pragma unroll
                for (int j = 0; j < 4; ++j)
                    acc[i][j] = __builtin_amdgcn_mfma_f32_16x16x32_f16(af[i], bf[j], acc[i][j], 0, 0, 0);
        }
        if (t < 7) __syncthreads();   // drains vmcnt: next tile's loads land
    }

    // ---- epilogue (register-only; no barrier needed after last step) ----
    if (mat == 0) {
        // Q: store head-major fp16 + sparsity (sum of squares per row)
        const int b = m0 >> 13;
        const int head = (n0 + wc * 64) >> 6;
        float bb[4];
#pragma unroll
        for (int j = 0; j < 4; ++j) bb[j] = bq[n0 + wc * 64 + j * 16 + c16];
        ushortT* qbase = Qbuf + ((size_t)(b * 8 + head) * 8192) * 64;
#pragma unroll
        for (int i = 0; i < 4; ++i)
#pragma unroll
            for (int r = 0; r < 4; ++r) {
                const int s = (m0 & 8191) + wr * 64 + i * 16 + quad * 4 + r;
                float p = 0.f;
#pragma unroll
                for (int j = 0; j < 4; ++j) {
                    float v = acc[i][j][r] + bb[j];
                    qbase[(size_t)s * 64 + j * 16 + c16] = f2h(v);
                    p = fmaf(v, v, p);
                }
                p += __shfl_xor(p, 1);
                p += __shfl_xor(p, 2);
                p += __shfl_xor(p, 4);
                p += __shfl_xor(p, 8);
                if (c16 == 0)
                    sparsity[((size_t)b * H_ + head) * S_ + s] = p;
            }
    } else if (mat == 1) {
        const int b = m0 >> 13;
        const int head = (n0 + wc * 64) >> 6;
        float bb[4];
#pragma unroll
        for (int j = 0; j < 4; ++j) bb[j] = bk[n0 + wc * 64 + j * 16 + c16];
        ushortT* kbase = Kbuf + ((size_t)(b * 8 + head) * 8192) * 64;
#pragma unroll
        for (int i = 0; i < 4; ++i)
#pragma unroll
            for (int r = 0; r < 4; ++r) {
                const int s = (m0 & 8191) + wr * 64 + i * 16 + quad * 4 + r;
#pragma unroll
                for (int j = 0; j < 4; ++j)
                    kbase[(size_t)s * 64 + j * 16 + c16] = f2h(acc[i][j][r] + bb[j]);
            }
    } else {
        // V transposed: VT[((b*8+head)*64 + dd)*8192 + s]
        const int b = m0 >> 13;
        const int sbase = (m0 & 8191) + wc * 64;
#pragma unroll
        for (int i = 0; i < 4; ++i)
#pragma unroll
            for (int r = 0; r < 4; ++r) {
                const int dcol = n0 + wr * 64 + i * 16 + quad * 4 + r;
                const int head = dcol >> 6, dd = dcol & 63;
                const float biasv = bv[dcol];
                ushortT* vrow = VT + ((size_t)(b * 8 + head) * 64 + dd) * 8192;
                float vsa = 0.f;
#pragma unroll
                for (int j = 0; j < 4; ++j) {
                    float v = acc[i][j][r] + biasv;
                    vrow[sbase + j * 16 + c16] = f2h(v);
                    vsa += v;
                }
                vsa += __shfl_xor(vsa, 1);
                vsa += __shfl_xor(vsa, 2);
                vsa += __shfl_xor(vsa, 4);
                vsa += __shfl_xor(vsa, 8);
                if (c16 == 0) atomicAdd(&vsum[b * 512 + dcol], vsa);
            }
    }
}

// ---------------------------------------------------------------------------
// Blocks [0,32): top-45 per (b,h) via 4-level byte radix-select.
// Blocks [32,64): outbase partial: outbase[b] += bo (ks==0) + k-slice
//   of mean_flat[b] @ Wo  (b = idx>>3, ks = (idx&7)>>1, d-half = idx&1).
// ---------------------------------------------------------------------------
__global__ __launch_bounds__(256) void topk_kernel(
    const float* __restrict__ sparsity, int* __restrict__ topidx,
    const float* __restrict__ vsum, const float* __restrict__ Wo,
    const float* __restrict__ bo, float* __restrict__ outbase)
{
    __shared__ unsigned vals[S_];        // 32 KB
    __shared__ unsigned hist[8][256];    // 8 KB
    __shared__ int ssum[256];
    __shared__ unsigned prefix_s;
    __shared__ int need_s;
    __shared__ int cnt_gt_s, cnt_eq_s;
    __shared__ int eqidx[64];
    const int tid = threadIdx.x;

    if (blockIdx.x >= 32) {
        const int idx = blockIdx.x - 32;
        const int b = idx >> 3, ks = (idx & 7) >> 1, dh = idx & 1;
        const int d = dh * 256 + tid;
        float acc = (ks == 0) ? bo[d] : 0.f;
        const int r0 = ks * 128;
        for (int r = r0; r < r0 + 128; ++r) {
            float mv = vsum[b * 512 + r] * (1.0f / S_);
            acc = fmaf(mv, Wo[(size_t)r * 512 + d], acc);
        }
        atomicAdd(&outbase[b * 512 + d], acc);
        return;
    }

    const int bh = blockIdx.x;
    const unsigned* sp = (const unsigned*)(sparsity + (size_t)bh * S_);
    for (int i = tid; i < S_; i += 256) vals[i] = sp[i];

    unsigned prefix = 0;
    int need = U_;
    const int rep = tid & 7;
    for (int level = 0; level < 4; ++level) {
        const int shift = 24 - level * 8;
#pragma unroll
        for (int r = 0; r < 8; ++r) hist[r][tid] = 0;
        __syncthreads();
        const unsigned pmask = (level == 0) ? 0u : (0xFFFFFFFFu << (shift + 8));
        for (int i = tid; i < S_; i += 256) {
            unsigned v = vals[i];
            if ((v & pmask) == prefix)
                atomicAdd(&hist[rep][(v >> shift) & 255], 1u);
        }
        __syncthreads();
        int bs = 0;
#pragma unroll
        for (int r = 0; r < 8; ++r) bs += (int)hist[r][tid];
        ssum[tid] = bs;
        __syncthreads();
        for (int off = 1; off < 256; off <<= 1) {
            int add = (tid + off < 256) ? ssum[tid + off] : 0;
            __syncthreads();
            ssum[tid] += add;
            __syncthreads();
        }
        int snext = (tid == 255) ? 0 : ssum[tid + 1];
        if (ssum[tid] >= need && snext < need) {
            prefix_s = prefix | ((unsigned)tid << shift);
            need_s = need - snext;
        }
        __syncthreads();
        prefix = prefix_s;
        need = need_s;
        __syncthreads();
    }
    const unsigned T = prefix;
    if (tid == 0) { cnt_gt_s = 0; cnt_eq_s = 0; }
    __syncthreads();
    for (int i = tid; i < S_; i += 256) {
        unsigned v = vals[i];
        if (v > T) {
            int p = atomicAdd(&cnt_gt_s, 1);
            topidx[bh * U_ + p] = i;
        } else if (v == T) {
            int p = atomicAdd(&cnt_eq_s, 1);
            if (p < 64) eqidx[p] = i;
        }
    }
    __syncthreads();
    if (tid == 0) {
        int rem = U_ - cnt_gt_s;
        int n = cnt_eq_s < 64 ? cnt_eq_s : 64;
        for (int a = 0; a < rem; ++a) {     // smallest indices among ties
            int best = 1 << 30, bj = 0;
            for (int j = 0; j < n; ++j)
                if (eqidx[j] < best) { best = eqidx[j]; bj = j; }
            topidx[bh * U_ + cnt_gt_s + a] = best;
            eqidx[bj] = 1 << 30;
        }
    }
}

// ---------------------------------------------------------------------------
// MFMA attention partials (fp16), no-max softmax (|s| bounded ~4).
// Grid (NCHUNK=16, 32 bh), 256 thr.  Block = 512 keys, 4 chunks of 128.
// ---------------------------------------------------------------------------
__global__ __launch_bounds__(256, 2) void attn_mfma(
    const ushortT* __restrict__ Qbuf, const ushortT* __restrict__ Kbuf,
    const ushortT* __restrict__ VT, const int* __restrict__ topidx,
    float* __restrict__ pl, float* __restrict__ pacc)
{
    __shared__ float sc[48 * 132];          // scores f32; P fp16 in-place
    __shared__ ushortT Qb[48 * 72];         // Q fp16, scale folded, padded

    const int tid = threadIdx.x;
    const int w = tid >> 6, lane = tid & 63;
    const int quad = lane >> 4, c16 = lane & 15;
    const int bh = blockIdx.y;
    const int s_base = blockIdx.x * 512;

    for (int i = tid; i < 48 * 64; i += 256) {
        int q = i >> 6, d = i & 63;
        float v = 0.f;
        if (q < U_) {
            int s = topidx[bh * U_ + q];
            v = h2f(Qbuf[((size_t)bh * 8192 + s) * 64 + d]) * 0.125f;
        }
        Qb[q * 72 + d] = f2h(v);
    }

    f32x4 O[3];
#pragma unroll
    for (int mt = 0; mt < 3; ++mt) O[mt] = (f32x4){0.f, 0.f, 0.f, 0.f};
    float lacc[12];
#pragma unroll
    for (int qi = 0; qi < 12; ++qi) lacc[qi] = 0.f;

    __syncthreads();

    half8 qa[3][2];
#pragma unroll
    for (int mt = 0; mt < 3; ++mt)
#pragma unroll
        for (int kk = 0; kk < 2; ++kk)
            qa[mt][kk] = *(const half8*)&Qb[(mt * 16 + c16) * 72 + kk * 32 + quad * 8];

    const ushortT* kb  = Kbuf + (size_t)bh * 8192 * 64;
    const ushortT* vtb = VT + ((size_t)bh * 64 + w * 16 + c16) * 8192;

    for (int ci = 0; ci < 4; ++ci) {
        const int s0 = s_base + ci * 128;

        half8 kf[2][2];
#pragma unroll
        for (int nt2 = 0; nt2 < 2; ++nt2)
#pragma unroll
            for (int kk = 0; kk < 2; ++kk)
                kf[nt2][kk] = *(const half8*)&kb[
                    (size_t)(s0 + w * 32 + nt2 * 16 + c16) * 64 + kk * 32 + quad * 8];
        f32x4 sacc[3][2];
#pragma unroll
        for (int mt = 0; mt < 3; ++mt)
#pragma unroll
            for (int nt2 = 0; nt2 < 2; ++nt2) {
                sacc[mt][nt2] = (f32x4){0.f, 0.f, 0.f, 0.f};
#pragma unroll
                for (int kk = 0; kk < 2; ++kk)
                    sacc[mt][nt2] = __builtin_amdgcn_mfma_f32_16x16x32_f16(
                        qa[mt][kk], kf[nt2][kk], sacc[mt][nt2], 0, 0, 0);
            }
#pragma unroll
        for (int mt = 0; mt < 3; ++mt)
#pragma unroll
            for (int nt2 = 0; nt2 < 2; ++nt2)
#pragma unroll
                for (int r = 0; r < 4; ++r)
                    sc[(mt * 16 + quad * 4 + r) * 132 + w * 32 + nt2 * 16 + c16] =
                        sacc[mt][nt2][r];
        __syncthreads();

        half8 vb[4];
#pragma unroll
        for (int kk = 0; kk < 4; ++kk)
            vb[kk] = *(const half8*)&vtb[s0 + kk * 32 + quad * 8];

#pragma unroll
        for (int qi = 0; qi < 12; ++qi) {
            const int q = w * 12 + qi;
            float x0 = sc[q * 132 + lane];
            float x1 = sc[q * 132 + 64 + lane];
            ushortT u0 = f2h(__expf(x0));
            ushortT u1 = f2h(__expf(x1));
            lacc[qi] += h2f(u0) + h2f(u1);
            ushortT* pr = (ushortT*)&sc[q * 132];
            pr[lane] = u0;
            pr[lane + 64] = u1;
        }
        __syncthreads();

#pragma unroll
        for (int mt = 0; mt < 3; ++mt)
#pragma unroll
            for (int kk = 0; kk < 4; ++kk) {
                half8 pa = *(const half8*)((const ushortT*)sc +
                    (size_t)(mt * 16 + c16) * 264 + kk * 32 + quad * 8);
                O[mt] = __builtin_amdgcn_mfma_f32_16x16x32_f16(pa, vb[kk], O[mt], 0, 0, 0);
            }
        __syncthreads();
    }

#pragma unroll
    for (int mt = 0; mt < 3; ++mt)
#pragma unroll
        for (int r = 0; r < 4; ++r) {
            const int q = mt * 16 + quad * 4 + r;
            if (q < U_)
                pacc[(((size_t)bh * NCHUNK + blockIdx.x) * U_ + q) * 64 + w * 16 + c16] =
                    O[mt][r];
        }
#pragma unroll
    for (int qi = 0; qi < 12; ++qi) {
        const int q = w * 12 + qi;
        float ssum = lacc[qi];
#pragma unroll
        for (int off = 1; off < 64; off <<= 1) ssum += __shfl_xor(ssum, off);
        if (lane == 0 && q < U_)
            pl[((size_t)bh * NCHUNK + blockIdx.x) * U_ + q] = ssum;
    }
}

// ---------------------------------------------------------------------------
// Broadcast fill: out[b,s,:] = out_base[b,:]
// ---------------------------------------------------------------------------
__global__ __launch_bounds__(256) void fill_kernel(
    const float* __restrict__ outbase, float* __restrict__ out)
{
    size_t gid = (size_t)blockIdx.x * 256 + threadIdx.x;
    size_t e0 = gid * 4;
    int b = (int)(e0 >> 22);          // 8192*512 = 2^22
    int col = (int)(e0 & 511);
    float4 v = *(const float4*)&outbase[b * 512 + col];
    *(float4*)&out[e0] = v;
}

// ---------------------------------------------------------------------------
// Merged combine + correction: block (q, bh).
// ---------------------------------------------------------------------------
__global__ __launch_bounds__(512) void corr_out_kernel(
    const float* __restrict__ pl, const float* __restrict__ pacc,
    const float* __restrict__ vsum, const float* __restrict__ Wo,
    const int* __restrict__ topidx, float* __restrict__ out)
{
    __shared__ float corrS[64];
    const int q = blockIdx.x, bh = blockIdx.y;
    const int b = bh >> 3, h = bh & 7, tid = threadIdx.x;
    if (tid < 64) {
        float L = 0.f, a = 0.f;
        for (int c = 0; c < NCHUNK; ++c) {
            L += pl[((size_t)bh * NCHUNK + c) * U_ + q];
            a += pacc[(((size_t)bh * NCHUNK + c) * U_ + q) * 64 + tid];
        }
        corrS[tid] = a / L - vsum[b * 512 + h * 64 + tid] * (1.0f / S_);
    }
    __syncthreads();
    const int s = topidx[bh * U_ + q];
    const int d = tid;
    float delta = 0.f;
#pragma unroll
    for (int r = 0; r < 64; ++r)
        delta = fmaf(corrS[r], Wo[(size_t)(h * 64 + r) * 512 + d], delta);
    atomicAdd(&out[((size_t)b * S_ + s) * 512 + d], delta);
}

// ---------------------------------------------------------------------------
extern "C" void kernel_launch(void* const* d_in, const int* in_sizes, int n_in,
                              void* d_out, int out_size, void* d_ws, size_t ws_size,
                              hipStream_t stream)
{
    const float* X  = (const float*)d_in[0];
    const float* Wq = (const float*)d_in[1];
    const float* bq = (const float*)d_in[2];
    const float* Wk = (const float*)d_in[3];
    const float* bk = (const float*)d_in[4];
    const float* Wv = (const float*)d_in[5];
    const float* bv = (const float*)d_in[6];
    const float* Wo = (const float*)d_in[7];
    const float* bo = (const float*)d_in[8];
    float* out = (float*)d_out;

    char* ws = (char*)d_ws;
    size_t off = 0;
    auto alloc = [&](size_t bytes) {
        void* p = ws + off;
        off = (off + bytes + 255) & ~(size_t)255;
        return p;
    };
    ushortT* Xf   = (ushortT*)alloc((size_t)B_ * S_ * D_ * 2);
    ushortT* Qbuf = (ushortT*)alloc((size_t)B_ * S_ * D_ * 2);
    ushortT* Kbuf = (ushortT*)alloc((size_t)B_ * S_ * D_ * 2);
    ushortT* VT   = (ushortT*)alloc((size_t)B_ * S_ * D_ * 2);
    ushortT* WqT  = (ushortT*)alloc((size_t)D_ * D_ * 2);
    ushortT* WkT  = (ushortT*)alloc((size_t)D_ * D_ * 2);
    ushortT* WvT  = (ushortT*)alloc((size_t)D_ * D_ * 2);
    float* sparsity = (float*)alloc((size_t)B_ * H_ * S_ * 4);
    int*   topidx   = (int*)alloc((size_t)B_ * H_ * U_ * 4);
    float* pl       = (float*)alloc((size_t)B_ * H_ * NCHUNK * U_ * 4);
    float* pacc     = (float*)alloc((size_t)B_ * H_ * NCHUNK * U_ * 64 * 4);
    float* vsum     = (float*)alloc((size_t)B_ * 512 * 4);
    float* outbase  = (float*)alloc((size_t)B_ * 512 * 4);

    prep_kernel<<<8960, 256, 0, stream>>>(X, Xf, Wq, Wk, Wv, WqT, WkT, WvT,
                                          vsum, outbase);
    qkv_mfma<<<dim3(256, 12), 256, 0, stream>>>(Xf, WqT, WkT, WvT,
                                                bq, bk, bv, Qbuf, Kbuf, VT,
                                                sparsity, vsum);
    topk_kernel<<<64, 256, 0, stream>>>(sparsity, topidx, vsum, Wo, bo, outbase);
    attn_mfma<<<dim3(NCHUNK, B_ * H_), 256, 0, stream>>>(Qbuf, Kbuf, VT, topidx,
                                                         pl, pacc);
    fill_kernel<<<(B_ * S_ * D_ / 4 + 255) / 256, 256, 0, stream>>>(outbase, out);
    corr_out_kernel<<<dim3(U_, B_ * H_), 512, 0, stream>>>(pl, pacc, vsum, Wo,
                                                           topidx, out);
}

// Round 2
// 299.121 us; speedup vs baseline: 1.0010x; 1.0010x over previous
//
#include <hip/hip_runtime.h>
#include <hip/hip_fp16.h>
#include <math.h>

#define B_ 4
#define S_ 8192
#define D_ 512
#define H_ 8
#define U_ 45            // int(5*ln(8193)) = 45
#define NCHUNK 16        // 512 keys per attention block

typedef unsigned short ushortT;
typedef __attribute__((ext_vector_type(8))) _Float16 half8;
typedef __attribute__((ext_vector_type(4))) float f32x4;

__device__ __forceinline__ ushortT f2h(float f) {
    return __half_as_ushort(__float2half(f));    // RNE
}
__device__ __forceinline__ float h2f(ushortT u) {
    return __half2float(__ushort_as_half(u));
}

__device__ __forceinline__ void gload_lds16(const ushortT* g, ushortT* l) {
    __builtin_amdgcn_global_load_lds(
        (const __attribute__((address_space(1))) void*)g,
        (__attribute__((address_space(3))) void*)l,
        16, 0, 0);
}

// ---------------------------------------------------------------------------
// Fused pre-pass: blocks [0,8192): X fp32 -> fp16 (block 0 zeroes vsum +
// outbase).  Blocks [8192, 8960): weight transpose+convert WT[n][k]=W[k][n].
// ---------------------------------------------------------------------------
__global__ __launch_bounds__(256) void prep_kernel(
    const float* __restrict__ X, ushortT* __restrict__ Xf,
    const float* __restrict__ Wq, const float* __restrict__ Wk,
    const float* __restrict__ Wv,
    ushortT* __restrict__ WqT, ushortT* __restrict__ WkT,
    ushortT* __restrict__ WvT,
    float* __restrict__ vsum, float* __restrict__ outbase)
{
    __shared__ float t[32][33];
    const int bx = blockIdx.x;
    if (bx < 8192) {
        if (bx == 0) {
            float4 z = {0.f, 0.f, 0.f, 0.f};
            *(float4*)&vsum[threadIdx.x * 8]        = z;
            *(float4*)&vsum[threadIdx.x * 8 + 4]    = z;
            *(float4*)&outbase[threadIdx.x * 8]     = z;
            *(float4*)&outbase[threadIdx.x * 8 + 4] = z;
        }
        size_t i = ((size_t)bx * 256 + threadIdx.x) * 8;
        float4 a = *(const float4*)(X + i);
        float4 b = *(const float4*)(X + i + 4);
        *(ushort4*)(Xf + i)     = make_ushort4(f2h(a.x), f2h(a.y), f2h(a.z), f2h(a.w));
        *(ushort4*)(Xf + i + 4) = make_ushort4(f2h(b.x), f2h(b.y), f2h(b.z), f2h(b.w));
    } else {
        const int idx = bx - 8192;
        const int z = idx >> 8, rem = idx & 255;
        const int r0 = (rem >> 4) * 32, c0 = (rem & 15) * 32;
        const float* W = (z == 0) ? Wq : (z == 1) ? Wk : Wv;
        ushortT* O = (z == 0) ? WqT : (z == 1) ? WkT : WvT;
        const int tx = threadIdx.x & 31, ty4 = (threadIdx.x >> 5) * 4;
#pragma unroll
        for (int i = 0; i < 4; ++i)
            t[ty4 + i][tx] = W[(size_t)(r0 + ty4 + i) * 512 + c0 + tx];
        __syncthreads();
#pragma unroll
        for (int i = 0; i < 4; ++i)
            O[(size_t)(c0 + ty4 + i) * 512 + r0 + tx] = f2h(t[tx][ty4 + i]);
    }
}

// ---------------------------------------------------------------------------
// MFMA QKV projection, fp16, BK=64, single-buffered (R8 config — the R10
// double-buffer regressed: LDS 64KB halved blocks/CU 3->2, MfmaUtil
// 23.5->19.5, dur 93.6->107.2us; implicit wave-level TLP at 3 blocks/CU
// beats intra-block pipelining here, matching m99/m100/m132).
//
// mode 0: Q-dispatch, grid (256, 4), y = n-tile, mat = 0.
// mode 1: KV-dispatch, grid (256, 9): y 0-3 K n-tiles, 4-7 V column-tiles,
//         y == 8 & x < 32: top-45 radix-select (reads sparsity produced by
//         the mode-0 dispatch) — rides fully overlapped under the KV GEMM.
//         Select path re-reads sparsity from global each pass (L2-resident,
//         1MB) instead of caching in LDS, so LDS stays 32KB (no union
//         occupancy hit).
// 128x128 tile, 4 waves 2x2, wave = 64x64.  8-chunk rotate swizzle: 0
// conflicts (verified SQ_LDS_BANK_CONFLICT=0).
// ---------------------------------------------------------------------------
__global__ __launch_bounds__(256, 2) void qkv_mfma(
    const ushortT* __restrict__ Xf,
    const ushortT* __restrict__ WqT, const ushortT* __restrict__ WkT,
    const ushortT* __restrict__ WvT,
    const float* __restrict__ bq, const float* __restrict__ bk,
    const float* __restrict__ bv,
    ushortT* __restrict__ Qbuf, ushortT* __restrict__ Kbuf,
    ushortT* __restrict__ VT,
    float* __restrict__ sparsity, float* __restrict__ vsum,
    int* __restrict__ topidx, int mode)
{
    __shared__ ushortT lds[2 * 128 * 64];   // A | B, 16KB each (32KB total)
    ushortT* As = lds;
    ushortT* Bs = lds + 8192;

    const int tid  = threadIdx.x;

    // ---------- top-k select path (KV dispatch, y == 8) ----------
    if (mode == 1 && blockIdx.y == 8) {
        if (blockIdx.x >= 32) return;
        // LDS aliases inside the 32KB gemm buffer:
        char* sm = (char*)lds;
        unsigned (*hist)[256] = (unsigned (*)[256])sm;          // 8KB
        int* ssum            = (int*)(sm + 8192);               // 1KB
        unsigned* prefix_s   = (unsigned*)(sm + 9216);
        int* need_s          = (int*)(sm + 9220);
        int* cnt_gt_s        = (int*)(sm + 9224);
        int* cnt_eq_s        = (int*)(sm + 9228);
        int* eqidx           = (int*)(sm + 9232);               // 64*4

        const int bh = blockIdx.x;
        const unsigned* sp = (const unsigned*)(sparsity + (size_t)bh * S_);

        unsigned prefix = 0;
        int need = U_;
        const int rep = tid & 7;
        for (int level = 0; level < 4; ++level) {
            const int shift = 24 - level * 8;
#pragma unroll
            for (int r = 0; r < 8; ++r) hist[r][tid] = 0;
            __syncthreads();
            const unsigned pmask = (level == 0) ? 0u : (0xFFFFFFFFu << (shift + 8));
            for (int i = tid; i < S_; i += 256) {
                unsigned v = sp[i];
                if ((v & pmask) == prefix)
                    atomicAdd(&hist[rep][(v >> shift) & 255], 1u);
            }
            __syncthreads();
            int bs = 0;
#pragma unroll
            for (int r = 0; r < 8; ++r) bs += (int)hist[r][tid];
            ssum[tid] = bs;
            __syncthreads();
            for (int off = 1; off < 256; off <<= 1) {
                int add = (tid + off < 256) ? ssum[tid + off] : 0;
                __syncthreads();
                ssum[tid] += add;
                __syncthreads();
            }
            int snext = (tid == 255) ? 0 : ssum[tid + 1];
            if (ssum[tid] >= need && snext < need) {
                *prefix_s = prefix | ((unsigned)tid << shift);
                *need_s = need - snext;
            }
            __syncthreads();
            prefix = *prefix_s;
            need = *need_s;
            __syncthreads();
        }
        const unsigned T = prefix;
        if (tid == 0) { *cnt_gt_s = 0; *cnt_eq_s = 0; }
        __syncthreads();
        for (int i = tid; i < S_; i += 256) {
            unsigned v = sp[i];
            if (v > T) {
                int p = atomicAdd(cnt_gt_s, 1);
                topidx[bh * U_ + p] = i;
            } else if (v == T) {
                int p = atomicAdd(cnt_eq_s, 1);
                if (p < 64) eqidx[p] = i;
            }
        }
        __syncthreads();
        if (tid == 0) {
            int rem = U_ - *cnt_gt_s;
            int n = *cnt_eq_s < 64 ? *cnt_eq_s : 64;
            for (int a = 0; a < rem; ++a) {     // smallest indices among ties
                int best = 1 << 30, bj = 0;
                for (int j = 0; j < n; ++j)
                    if (eqidx[j] < best) { best = eqidx[j]; bj = j; }
                topidx[bh * U_ + *cnt_gt_s + a] = best;
                eqidx[bj] = 1 << 30;
            }
        }
        return;
    }

    // ---------- GEMM path ----------
    const int w    = tid >> 6, lane = tid & 63;
    const int quad = lane >> 4, c16 = lane & 15;
    const int wr   = w >> 1,  wc  = w & 1;
    const int mat  = (mode == 0) ? 0 : 1 + (blockIdx.y >> 2);   // 0=Q 1=K 2=V
    const int nt   = (mode == 0) ? blockIdx.y : (blockIdx.y & 3);
    const int m0   = blockIdx.x * 128;
    const int n0   = nt * 128;

    const int srowL = lane >> 3;                            // 0..7 within wave
    const int slc   = (((lane & 7) - (srowL & 7)) & 7) * 8; // swizzled src chunk
    const int rrot  = c16 & 7;

    const ushortT* Ag = (mat == 2) ? WvT : Xf;
    const ushortT* Bg = (mat == 0) ? WqT : (mat == 1) ? WkT : Xf;
    const int arow0 = (mat == 2) ? n0 : m0;
    const int brow0 = (mat == 2) ? m0 : n0;

    f32x4 acc[4][4];
#pragma unroll
    for (int i = 0; i < 4; ++i)
#pragma unroll
        for (int j = 0; j < 4; ++j) acc[i][j] = (f32x4){0.f, 0.f, 0.f, 0.f};

    for (int k0 = 0; k0 < 512; k0 += 64) {
        __syncthreads();
#pragma unroll
        for (int c = 0; c < 4; ++c) {
            const int R = c * 32 + w * 8 + srowL;
            const int lbase = c * 2048 + w * 512;          // halves
            gload_lds16(Ag + (size_t)(arow0 + R) * 512 + k0 + slc, As + lbase);
            gload_lds16(Bg + (size_t)(brow0 + R) * 512 + k0 + slc, Bs + lbase);
        }
        __syncthreads();
#pragma unroll
        for (int kk = 0; kk < 2; ++kk) {
            const int phk = (((kk * 4 + quad) + rrot) & 7) * 8;
            half8 af[4], bf[4];
#pragma unroll
            for (int i = 0; i < 4; ++i) {
                af[i] = *(const half8*)&As[(wr * 64 + i * 16 + c16) * 64 + phk];
                bf[i] = *(const half8*)&Bs[(wc * 64 + i * 16 + c16) * 64 + phk];
            }
#pragma unroll
            for (int i = 0; i < 4; ++i)
#pragma unroll
                for (int j = 0; j < 4; ++j)
                    acc[i][j] = __builtin_amdgcn_mfma_f32_16x16x32_f16(af[i], bf[j], acc[i][j], 0, 0, 0);
        }
    }

    // ---- epilogue ----
    if (mat == 0) {
        // Q: store head-major fp16 + sparsity (sum of squares per row)
        const int b = m0 >> 13;
        const int head = (n0 + wc * 64) >> 6;
        float bb[4];
#pragma unroll
        for (int j = 0; j < 4; ++j) bb[j] = bq[n0 + wc * 64 + j * 16 + c16];
        ushortT* qbase = Qbuf + ((size_t)(b * 8 + head) * 8192) * 64;
#pragma unroll
        for (int i = 0; i < 4; ++i)
#pragma unroll
            for (int r = 0; r < 4; ++r) {
                const int s = (m0 & 8191) + wr * 64 + i * 16 + quad * 4 + r;
                float p = 0.f;
#pragma unroll
                for (int j = 0; j < 4; ++j) {
                    float v = acc[i][j][r] + bb[j];
                    qbase[(size_t)s * 64 + j * 16 + c16] = f2h(v);
                    p = fmaf(v, v, p);
                }
                p += __shfl_xor(p, 1);
                p += __shfl_xor(p, 2);
                p += __shfl_xor(p, 4);
                p += __shfl_xor(p, 8);
                if (c16 == 0)
                    sparsity[((size_t)b * H_ + head) * S_ + s] = p;
            }
    } else if (mat == 1) {
        const int b = m0 >> 13;
        const int head = (n0 + wc * 64) >> 6;
        float bb[4];
#pragma unroll
        for (int j = 0; j < 4; ++j) bb[j] = bk[n0 + wc * 64 + j * 16 + c16];
        ushortT* kbase = Kbuf + ((size_t)(b * 8 + head) * 8192) * 64;
#pragma unroll
        for (int i = 0; i < 4; ++i)
#pragma unroll
            for (int r = 0; r < 4; ++r) {
                const int s = (m0 & 8191) + wr * 64 + i * 16 + quad * 4 + r;
#pragma unroll
                for (int j = 0; j < 4; ++j)
                    kbase[(size_t)s * 64 + j * 16 + c16] = f2h(acc[i][j][r] + bb[j]);
            }
    } else {
        // V transposed: VT[((b*8+head)*64 + dd)*8192 + s]
        const int b = m0 >> 13;
        const int sbase = (m0 & 8191) + wc * 64;
#pragma unroll
        for (int i = 0; i < 4; ++i)
#pragma unroll
            for (int r = 0; r < 4; ++r) {
                const int dcol = n0 + wr * 64 + i * 16 + quad * 4 + r;
                const int head = dcol >> 6, dd = dcol & 63;
                const float biasv = bv[dcol];
                ushortT* vrow = VT + ((size_t)(b * 8 + head) * 64 + dd) * 8192;
                float vsa = 0.f;
#pragma unroll
                for (int j = 0; j < 4; ++j) {
                    float v = acc[i][j][r] + biasv;
                    vrow[sbase + j * 16 + c16] = f2h(v);
                    vsa += v;
                }
                vsa += __shfl_xor(vsa, 1);
                vsa += __shfl_xor(vsa, 2);
                vsa += __shfl_xor(vsa, 4);
                vsa += __shfl_xor(vsa, 8);
                if (c16 == 0) atomicAdd(&vsum[b * 512 + dcol], vsa);
            }
    }
}

// ---------------------------------------------------------------------------
// MFMA attention partials (fp16), no-max softmax (|s| bounded ~4).
// Grid (NCHUNK+1 = 17, 32 bh), 256 thr.  Block = 512 keys, 4 chunks of 128.
// x == 16 column: outbase partial blocks (moved from the old topk kernel):
//   outbase[b] += bo (ks==0) + k-slice of mean_flat[b] @ Wo, idx = blockIdx.y.
//   These only need vsum (complete after the KV dispatch) and overlap attn.
// ---------------------------------------------------------------------------
__global__ __launch_bounds__(256, 2) void attn_mfma(
    const ushortT* __restrict__ Qbuf, const ushortT* __restrict__ Kbuf,
    const ushortT* __restrict__ VT, const int* __restrict__ topidx,
    float* __restrict__ pl, float* __restrict__ pacc,
    const float* __restrict__ vsum, const float* __restrict__ Wo,
    const float* __restrict__ bo, float* __restrict__ outbase)
{
    __shared__ float sc[48 * 132];          // scores f32; P fp16 in-place
    __shared__ ushortT Qb[48 * 72];         // Q fp16, scale folded, padded

    const int tid = threadIdx.x;

    if (blockIdx.x == 16) {
        const int idx = blockIdx.y;          // 0..31
        const int b = idx >> 3, ks = (idx & 7) >> 1, dh = idx & 1;
        const int d = dh * 256 + tid;
        float acc = (ks == 0) ? bo[d] : 0.f;
        const int r0 = ks * 128;
        for (int r = r0; r < r0 + 128; ++r) {
            float mv = vsum[b * 512 + r] * (1.0f / S_);
            acc = fmaf(mv, Wo[(size_t)r * 512 + d], acc);
        }
        atomicAdd(&outbase[b * 512 + d], acc);
        return;
    }

    const int w = tid >> 6, lane = tid & 63;
    const int quad = lane >> 4, c16 = lane & 15;
    const int bh = blockIdx.y;
    const int s_base = blockIdx.x * 512;

    for (int i = tid; i < 48 * 64; i += 256) {
        int q = i >> 6, d = i & 63;
        float v = 0.f;
        if (q < U_) {
            int s = topidx[bh * U_ + q];
            v = h2f(Qbuf[((size_t)bh * 8192 + s) * 64 + d]) * 0.125f;
        }
        Qb[q * 72 + d] = f2h(v);
    }

    f32x4 O[3];
#pragma unroll
    for (int mt = 0; mt < 3; ++mt) O[mt] = (f32x4){0.f, 0.f, 0.f, 0.f};
    float lacc[12];
#pragma unroll
    for (int qi = 0; qi < 12; ++qi) lacc[qi] = 0.f;

    __syncthreads();

    half8 qa[3][2];
#pragma unroll
    for (int mt = 0; mt < 3; ++mt)
#pragma unroll
        for (int kk = 0; kk < 2; ++kk)
            qa[mt][kk] = *(const half8*)&Qb[(mt * 16 + c16) * 72 + kk * 32 + quad * 8];

    const ushortT* kb  = Kbuf + (size_t)bh * 8192 * 64;
    const ushortT* vtb = VT + ((size_t)bh * 64 + w * 16 + c16) * 8192;

    for (int ci = 0; ci < 4; ++ci) {
        const int s0 = s_base + ci * 128;

        half8 kf[2][2];
#pragma unroll
        for (int nt2 = 0; nt2 < 2; ++nt2)
#pragma unroll
            for (int kk = 0; kk < 2; ++kk)
                kf[nt2][kk] = *(const half8*)&kb[
                    (size_t)(s0 + w * 32 + nt2 * 16 + c16) * 64 + kk * 32 + quad * 8];
        f32x4 sacc[3][2];
#pragma unroll
        for (int mt = 0; mt < 3; ++mt)
#pragma unroll
            for (int nt2 = 0; nt2 < 2; ++nt2) {
                sacc[mt][nt2] = (f32x4){0.f, 0.f, 0.f, 0.f};
#pragma unroll
                for (int kk = 0; kk < 2; ++kk)
                    sacc[mt][nt2] = __builtin_amdgcn_mfma_f32_16x16x32_f16(
                        qa[mt][kk], kf[nt2][kk], sacc[mt][nt2], 0, 0, 0);
            }
#pragma unroll
        for (int mt = 0; mt < 3; ++mt)
#pragma unroll
            for (int nt2 = 0; nt2 < 2; ++nt2)
#pragma unroll
                for (int r = 0; r < 4; ++r)
                    sc[(mt * 16 + quad * 4 + r) * 132 + w * 32 + nt2 * 16 + c16] =
                        sacc[mt][nt2][r];
        __syncthreads();

        half8 vb[4];
#pragma unroll
        for (int kk = 0; kk < 4; ++kk)
            vb[kk] = *(const half8*)&vtb[s0 + kk * 32 + quad * 8];

#pragma unroll
        for (int qi = 0; qi < 12; ++qi) {
            const int q = w * 12 + qi;
            float x0 = sc[q * 132 + lane];
            float x1 = sc[q * 132 + 64 + lane];
            ushortT u0 = f2h(__expf(x0));
            ushortT u1 = f2h(__expf(x1));
            lacc[qi] += h2f(u0) + h2f(u1);
            ushortT* pr = (ushortT*)&sc[q * 132];
            pr[lane] = u0;
            pr[lane + 64] = u1;
        }
        __syncthreads();

#pragma unroll
        for (int mt = 0; mt < 3; ++mt)
#pragma unroll
            for (int kk = 0; kk < 4; ++kk) {
                half8 pa = *(const half8*)((const ushortT*)sc +
                    (size_t)(mt * 16 + c16) * 264 + kk * 32 + quad * 8);
                O[mt] = __builtin_amdgcn_mfma_f32_16x16x32_f16(pa, vb[kk], O[mt], 0, 0, 0);
            }
        __syncthreads();
    }

#pragma unroll
    for (int mt = 0; mt < 3; ++mt)
#pragma unroll
        for (int r = 0; r < 4; ++r) {
            const int q = mt * 16 + quad * 4 + r;
            if (q < U_)
                pacc[(((size_t)bh * NCHUNK + blockIdx.x) * U_ + q) * 64 + w * 16 + c16] =
                    O[mt][r];
        }
#pragma unroll
    for (int qi = 0; qi < 12; ++qi) {
        const int q = w * 12 + qi;
        float ssum = lacc[qi];
#pragma unroll
        for (int off = 1; off < 64; off <<= 1) ssum += __shfl_xor(ssum, off);
        if (lane == 0 && q < U_)
            pl[((size_t)bh * NCHUNK + blockIdx.x) * U_ + q] = ssum;
    }
}

// ---------------------------------------------------------------------------
// Broadcast fill: out[b,s,:] = out_base[b,:]
// ---------------------------------------------------------------------------
__global__ __launch_bounds__(256) void fill_kernel(
    const float* __restrict__ outbase, float* __restrict__ out)
{
    size_t gid = (size_t)blockIdx.x * 256 + threadIdx.x;
    size_t e0 = gid * 4;
    int b = (int)(e0 >> 22);          // 8192*512 = 2^22
    int col = (int)(e0 & 511);
    float4 v = *(const float4*)&outbase[b * 512 + col];
    *(float4*)&out[e0] = v;
}

// ---------------------------------------------------------------------------
// Merged combine + correction: block (q, bh).
// ---------------------------------------------------------------------------
__global__ __launch_bounds__(512) void corr_out_kernel(
    const float* __restrict__ pl, const float* __restrict__ pacc,
    const float* __restrict__ vsum, const float* __restrict__ Wo,
    const int* __restrict__ topidx, float* __restrict__ out)
{
    __shared__ float corrS[64];
    const int q = blockIdx.x, bh = blockIdx.y;
    const int b = bh >> 3, h = bh & 7, tid = threadIdx.x;
    if (tid < 64) {
        float L = 0.f, a = 0.f;
        for (int c = 0; c < NCHUNK; ++c) {
            L += pl[((size_t)bh * NCHUNK + c) * U_ + q];
            a += pacc[(((size_t)bh * NCHUNK + c) * U_ + q) * 64 + tid];
        }
        corrS[tid] = a / L - vsum[b * 512 + h * 64 + tid] * (1.0f / S_);
    }
    __syncthreads();
    const int s = topidx[bh * U_ + q];
    const int d = tid;
    float delta = 0.f;
#pragma unroll
    for (int r = 0; r < 64; ++r)
        delta = fmaf(corrS[r], Wo[(size_t)(h * 64 + r) * 512 + d], delta);
    atomicAdd(&out[((size_t)b * S_ + s) * 512 + d], delta);
}

// ---------------------------------------------------------------------------
extern "C" void kernel_launch(void* const* d_in, const int* in_sizes, int n_in,
                              void* d_out, int out_size, void* d_ws, size_t ws_size,
                              hipStream_t stream)
{
    const float* X  = (const float*)d_in[0];
    const float* Wq = (const float*)d_in[1];
    const float* bq = (const float*)d_in[2];
    const float* Wk = (const float*)d_in[3];
    const float* bk = (const float*)d_in[4];
    const float* Wv = (const float*)d_in[5];
    const float* bv = (const float*)d_in[6];
    const float* Wo = (const float*)d_in[7];
    const float* bo = (const float*)d_in[8];
    float* out = (float*)d_out;

    char* ws = (char*)d_ws;
    size_t off = 0;
    auto alloc = [&](size_t bytes) {
        void* p = ws + off;
        off = (off + bytes + 255) & ~(size_t)255;
        return p;
    };
    ushortT* Xf   = (ushortT*)alloc((size_t)B_ * S_ * D_ * 2);
    ushortT* Qbuf = (ushortT*)alloc((size_t)B_ * S_ * D_ * 2);
    ushortT* Kbuf = (ushortT*)alloc((size_t)B_ * S_ * D_ * 2);
    ushortT* VT   = (ushortT*)alloc((size_t)B_ * S_ * D_ * 2);
    ushortT* WqT  = (ushortT*)alloc((size_t)D_ * D_ * 2);
    ushortT* WkT  = (ushortT*)alloc((size_t)D_ * D_ * 2);
    ushortT* WvT  = (ushortT*)alloc((size_t)D_ * D_ * 2);
    float* sparsity = (float*)alloc((size_t)B_ * H_ * S_ * 4);
    int*   topidx   = (int*)alloc((size_t)B_ * H_ * U_ * 4);
    float* pl       = (float*)alloc((size_t)B_ * H_ * NCHUNK * U_ * 4);
    float* pacc     = (float*)alloc((size_t)B_ * H_ * NCHUNK * U_ * 64 * 4);
    float* vsum     = (float*)alloc((size_t)B_ * 512 * 4);
    float* outbase  = (float*)alloc((size_t)B_ * 512 * 4);

    prep_kernel<<<8960, 256, 0, stream>>>(X, Xf, Wq, Wk, Wv, WqT, WkT, WvT,
                                          vsum, outbase);
    // Q projection (+ sparsity), then KV projection with top-k select
    // overlapped as grid row y==8.
    qkv_mfma<<<dim3(256, 4), 256, 0, stream>>>(Xf, WqT, WkT, WvT,
                                               bq, bk, bv, Qbuf, Kbuf, VT,
                                               sparsity, vsum, topidx, 0);
    qkv_mfma<<<dim3(256, 9), 256, 0, stream>>>(Xf, WqT, WkT, WvT,
                                               bq, bk, bv, Qbuf, Kbuf, VT,
                                               sparsity, vsum, topidx, 1);
    attn_mfma<<<dim3(NCHUNK + 1, B_ * H_), 256, 0, stream>>>(
        Qbuf, Kbuf, VT, topidx, pl, pacc, vsum, Wo, bo, outbase);
    fill_kernel<<<(B_ * S_ * D_ / 4 + 255) / 256, 256, 0, stream>>>(outbase, out);
    corr_out_kernel<<<dim3(U_, B_ * H_), 512, 0, stream>>>(pl, pacc, vsum, Wo,
                                                           topidx, out);
}

// Round 3
// 279.636 us; speedup vs baseline: 1.0708x; 1.0697x over previous
//
#include <hip/hip_runtime.h>
#include <hip/hip_fp16.h>
#include <math.h>

#define B_ 4
#define S_ 8192
#define D_ 512
#define H_ 8
#define U_ 45            // int(5*ln(8193)) = 45
#define NCHUNK 16        // 512 keys per attention block

typedef unsigned short ushortT;
typedef __attribute__((ext_vector_type(8))) _Float16 half8;
typedef __attribute__((ext_vector_type(4))) float f32x4;

__device__ __forceinline__ ushortT f2h(float f) {
    return __half_as_ushort(__float2half(f));    // RNE
}
__device__ __forceinline__ float h2f(ushortT u) {
    return __half2float(__ushort_as_half(u));
}

__device__ __forceinline__ void gload_lds16(const ushortT* g, ushortT* l) {
    __builtin_amdgcn_global_load_lds(
        (const __attribute__((address_space(1))) void*)g,
        (__attribute__((address_space(3))) void*)l,
        16, 0, 0);
}

// ---------------------------------------------------------------------------
// Fused pre-pass: blocks [0,8192): X fp32 -> fp16 (block 0 zeroes vsum +
// outbase).  Blocks [8192, 8960): weight transpose+convert WT[n][k]=W[k][n].
// ---------------------------------------------------------------------------
__global__ __launch_bounds__(256) void prep_kernel(
    const float* __restrict__ X, ushortT* __restrict__ Xf,
    const float* __restrict__ Wq, const float* __restrict__ Wk,
    const float* __restrict__ Wv,
    ushortT* __restrict__ WqT, ushortT* __restrict__ WkT,
    ushortT* __restrict__ WvT,
    float* __restrict__ vsum, float* __restrict__ outbase)
{
    __shared__ float t[32][33];
    const int bx = blockIdx.x;
    if (bx < 8192) {
        if (bx == 0) {
            float4 z = {0.f, 0.f, 0.f, 0.f};
            *(float4*)&vsum[threadIdx.x * 8]        = z;
            *(float4*)&vsum[threadIdx.x * 8 + 4]    = z;
            *(float4*)&outbase[threadIdx.x * 8]     = z;
            *(float4*)&outbase[threadIdx.x * 8 + 4] = z;
        }
        size_t i = ((size_t)bx * 256 + threadIdx.x) * 8;
        float4 a = *(const float4*)(X + i);
        float4 b = *(const float4*)(X + i + 4);
        *(ushort4*)(Xf + i)     = make_ushort4(f2h(a.x), f2h(a.y), f2h(a.z), f2h(a.w));
        *(ushort4*)(Xf + i + 4) = make_ushort4(f2h(b.x), f2h(b.y), f2h(b.z), f2h(b.w));
    } else {
        const int idx = bx - 8192;
        const int z = idx >> 8, rem = idx & 255;
        const int r0 = (rem >> 4) * 32, c0 = (rem & 15) * 32;
        const float* W = (z == 0) ? Wq : (z == 1) ? Wk : Wv;
        ushortT* O = (z == 0) ? WqT : (z == 1) ? WkT : WvT;
        const int tx = threadIdx.x & 31, ty4 = (threadIdx.x >> 5) * 4;
#pragma unroll
        for (int i = 0; i < 4; ++i)
            t[ty4 + i][tx] = W[(size_t)(r0 + ty4 + i) * 512 + c0 + tx];
        __syncthreads();
#pragma unroll
        for (int i = 0; i < 4; ++i)
            O[(size_t)(c0 + ty4 + i) * 512 + r0 + tx] = f2h(t[tx][ty4 + i]);
    }
}

// ---------------------------------------------------------------------------
// MFMA QKV projection, fp16, BK=64, single-buffered 2-barrier loop (R8
// sync structure — R10 dbuf regressed, R11 dispatch-split regressed).
// R12: 512-thread blocks, wave-split stream fusion:
//   y 0-3 (fused QK): one 128-row Xf A-tile staged ONCE, waves 0-3 compute
//     the 128x128 Q-tile (B=WqT), waves 4-7 the K-tile (B=WkT).  Per-wave
//     regs unchanged (1 acc[4][4] each) -> no R9-style spill; A staging
//     halves for QK; MFMA per barrier doubles (256/block/K-step).
//   y 4-5 (V): A = WvT 256 rows, B = Xf 128 rows, waves 4x2.
// LDS 48KB (3 x 16KB), 2 blocks/CU = 16 waves/CU (same residency as R8's
// 4 x 4-wave blocks).  8-chunk rotate swizzle preserved: row mod 8 ==
// c16 mod 8 for all read patterns.
// ---------------------------------------------------------------------------
__global__ __launch_bounds__(512, 2) void qkv_mfma(
    const ushortT* __restrict__ Xf,
    const ushortT* __restrict__ WqT, const ushortT* __restrict__ WkT,
    const ushortT* __restrict__ WvT,
    const float* __restrict__ bq, const float* __restrict__ bk,
    const float* __restrict__ bv,
    ushortT* __restrict__ Qbuf, ushortT* __restrict__ Kbuf,
    ushortT* __restrict__ VT,
    float* __restrict__ sparsity, float* __restrict__ vsum)
{
    __shared__ ushortT lds[3 * 128 * 64];   // 48KB: A | B0 | B1 (16KB each)

    const int tid  = threadIdx.x;
    const int w    = tid >> 6, lane = tid & 63;
    const int quad = lane >> 4, c16 = lane & 15;
    const bool fusedQK = (blockIdx.y < 4);
    const int stream = w >> 2;               // QK: 0=Q wave, 1=K wave
    const int aw   = fusedQK ? ((w >> 1) & 1) : (w >> 1);  // A-dir wave idx
    const int bw   = w & 1;                                 // B-dir wave idx
    const int m0   = blockIdx.x * 128;
    const int n0   = fusedQK ? (blockIdx.y * 128) : ((blockIdx.y - 4) * 256);

    const int srowL = lane >> 3;                            // 0..7 within wave
    const int slc   = (((lane & 7) - (srowL & 7)) & 7) * 8; // swizzled src chunk
    const int rrot  = c16 & 7;

    const ushortT* Brd = fusedQK ? (lds + 8192 + stream * 8192) : (lds + 16384);
    const int awBase = aw * 64;
    const int bwBase = bw * 64;

    f32x4 acc[4][4];
#pragma unroll
    for (int i = 0; i < 4; ++i)
#pragma unroll
        for (int j = 0; j < 4; ++j) acc[i][j] = (f32x4){0.f, 0.f, 0.f, 0.f};

    for (int k0 = 0; k0 < 512; k0 += 64) {
        __syncthreads();
        if (fusedQK) {
#pragma unroll
            for (int c = 0; c < 2; ++c) {
                const int R  = c * 64 + w * 8 + srowL;
                const int lb = c * 4096 + w * 512;
                gload_lds16(Xf  + (size_t)(m0 + R) * 512 + k0 + slc, lds + lb);
                gload_lds16(WqT + (size_t)(n0 + R) * 512 + k0 + slc, lds + 8192 + lb);
                gload_lds16(WkT + (size_t)(n0 + R) * 512 + k0 + slc, lds + 16384 + lb);
            }
        } else {
#pragma unroll
            for (int c = 0; c < 4; ++c) {
                const int R = c * 64 + w * 8 + srowL;
                gload_lds16(WvT + (size_t)(n0 + R) * 512 + k0 + slc,
                            lds + c * 4096 + w * 512);
            }
#pragma unroll
            for (int c = 0; c < 2; ++c) {
                const int R = c * 64 + w * 8 + srowL;
                gload_lds16(Xf + (size_t)(m0 + R) * 512 + k0 + slc,
                            lds + 16384 + c * 4096 + w * 512);
            }
        }
        __syncthreads();
#pragma unroll
        for (int kk = 0; kk < 2; ++kk) {
            const int phk = (((kk * 4 + quad) + rrot) & 7) * 8;
            half8 af[4], bf[4];
#pragma unroll
            for (int i = 0; i < 4; ++i) {
                af[i] = *(const half8*)&lds[(awBase + i * 16 + c16) * 64 + phk];
                bf[i] = *(const half8*)&Brd[(bwBase + i * 16 + c16) * 64 + phk];
            }
#pragma unroll
            for (int i = 0; i < 4; ++i)
#pragma unroll
                for (int j = 0; j < 4; ++j)
                    acc[i][j] = __builtin_amdgcn_mfma_f32_16x16x32_f16(af[i], bf[j], acc[i][j], 0, 0, 0);
        }
    }

    // ---- epilogue ----
    const int b = m0 >> 13;
    if (fusedQK && stream == 0) {
        // Q: store head-major fp16 + sparsity (sum of squares per row)
        const int head = (n0 + bw * 64) >> 6;
        float bb[4];
#pragma unroll
        for (int j = 0; j < 4; ++j) bb[j] = bq[n0 + bw * 64 + j * 16 + c16];
        ushortT* qbase = Qbuf + ((size_t)(b * 8 + head) * 8192) * 64;
#pragma unroll
        for (int i = 0; i < 4; ++i)
#pragma unroll
            for (int r = 0; r < 4; ++r) {
                const int s = (m0 & 8191) + awBase + i * 16 + quad * 4 + r;
                float p = 0.f;
#pragma unroll
                for (int j = 0; j < 4; ++j) {
                    float v = acc[i][j][r] + bb[j];
                    qbase[(size_t)s * 64 + j * 16 + c16] = f2h(v);
                    p = fmaf(v, v, p);
                }
                p += __shfl_xor(p, 1);
                p += __shfl_xor(p, 2);
                p += __shfl_xor(p, 4);
                p += __shfl_xor(p, 8);
                if (c16 == 0)
                    sparsity[((size_t)b * H_ + head) * S_ + s] = p;
            }
    } else if (fusedQK) {
        const int head = (n0 + bw * 64) >> 6;
        float bb[4];
#pragma unroll
        for (int j = 0; j < 4; ++j) bb[j] = bk[n0 + bw * 64 + j * 16 + c16];
        ushortT* kbase = Kbuf + ((size_t)(b * 8 + head) * 8192) * 64;
#pragma unroll
        for (int i = 0; i < 4; ++i)
#pragma unroll
            for (int r = 0; r < 4; ++r) {
                const int s = (m0 & 8191) + awBase + i * 16 + quad * 4 + r;
#pragma unroll
                for (int j = 0; j < 4; ++j)
                    kbase[(size_t)s * 64 + j * 16 + c16] = f2h(acc[i][j][r] + bb[j]);
            }
    } else {
        // V transposed: VT[((b*8+head)*64 + dd)*8192 + s]
        const int sbase = (m0 & 8191) + bwBase;
#pragma unroll
        for (int i = 0; i < 4; ++i)
#pragma unroll
            for (int r = 0; r < 4; ++r) {
                const int dcol = n0 + awBase + i * 16 + quad * 4 + r;
                const int head = dcol >> 6, dd = dcol & 63;
                const float biasv = bv[dcol];
                ushortT* vrow = VT + ((size_t)(b * 8 + head) * 64 + dd) * 8192;
                float vsa = 0.f;
#pragma unroll
                for (int j = 0; j < 4; ++j) {
                    float v = acc[i][j][r] + biasv;
                    vrow[sbase + j * 16 + c16] = f2h(v);
                    vsa += v;
                }
                vsa += __shfl_xor(vsa, 1);
                vsa += __shfl_xor(vsa, 2);
                vsa += __shfl_xor(vsa, 4);
                vsa += __shfl_xor(vsa, 8);
                if (c16 == 0) atomicAdd(&vsum[b * 512 + dcol], vsa);
            }
    }
}

// ---------------------------------------------------------------------------
// Blocks [0,32): top-45 per (b,h) via 4-level byte radix-select.
// Blocks [32,64): outbase partial: outbase[b] += bo (ks==0) + k-slice
//   of mean_flat[b] @ Wo  (b = idx>>3, ks = (idx&7)>>1, d-half = idx&1).
// ---------------------------------------------------------------------------
__global__ __launch_bounds__(256) void topk_kernel(
    const float* __restrict__ sparsity, int* __restrict__ topidx,
    const float* __restrict__ vsum, const float* __restrict__ Wo,
    const float* __restrict__ bo, float* __restrict__ outbase)
{
    __shared__ unsigned vals[S_];        // 32 KB
    __shared__ unsigned hist[8][256];    // 8 KB
    __shared__ int ssum[256];
    __shared__ unsigned prefix_s;
    __shared__ int need_s;
    __shared__ int cnt_gt_s, cnt_eq_s;
    __shared__ int eqidx[64];
    const int tid = threadIdx.x;

    if (blockIdx.x >= 32) {
        const int idx = blockIdx.x - 32;
        const int b = idx >> 3, ks = (idx & 7) >> 1, dh = idx & 1;
        const int d = dh * 256 + tid;
        float acc = (ks == 0) ? bo[d] : 0.f;
        const int r0 = ks * 128;
        for (int r = r0; r < r0 + 128; ++r) {
            float mv = vsum[b * 512 + r] * (1.0f / S_);
            acc = fmaf(mv, Wo[(size_t)r * 512 + d], acc);
        }
        atomicAdd(&outbase[b * 512 + d], acc);
        return;
    }

    const int bh = blockIdx.x;
    const unsigned* sp = (const unsigned*)(sparsity + (size_t)bh * S_);
    for (int i = tid; i < S_; i += 256) vals[i] = sp[i];

    unsigned prefix = 0;
    int need = U_;
    const int rep = tid & 7;
    for (int level = 0; level < 4; ++level) {
        const int shift = 24 - level * 8;
#pragma unroll
        for (int r = 0; r < 8; ++r) hist[r][tid] = 0;
        __syncthreads();
        const unsigned pmask = (level == 0) ? 0u : (0xFFFFFFFFu << (shift + 8));
        for (int i = tid; i < S_; i += 256) {
            unsigned v = vals[i];
            if ((v & pmask) == prefix)
                atomicAdd(&hist[rep][(v >> shift) & 255], 1u);
        }
        __syncthreads();
        int bs = 0;
#pragma unroll
        for (int r = 0; r < 8; ++r) bs += (int)hist[r][tid];
        ssum[tid] = bs;
        __syncthreads();
        for (int off = 1; off < 256; off <<= 1) {
            int add = (tid + off < 256) ? ssum[tid + off] : 0;
            __syncthreads();
            ssum[tid] += add;
            __syncthreads();
        }
        int snext = (tid == 255) ? 0 : ssum[tid + 1];
        if (ssum[tid] >= need && snext < need) {
            prefix_s = prefix | ((unsigned)tid << shift);
            need_s = need - snext;
        }
        __syncthreads();
        prefix = prefix_s;
        need = need_s;
        __syncthreads();
    }
    const unsigned T = prefix;
    if (tid == 0) { cnt_gt_s = 0; cnt_eq_s = 0; }
    __syncthreads();
    for (int i = tid; i < S_; i += 256) {
        unsigned v = vals[i];
        if (v > T) {
            int p = atomicAdd(&cnt_gt_s, 1);
            topidx[bh * U_ + p] = i;
        } else if (v == T) {
            int p = atomicAdd(&cnt_eq_s, 1);
            if (p < 64) eqidx[p] = i;
        }
    }
    __syncthreads();
    if (tid == 0) {
        int rem = U_ - cnt_gt_s;
        int n = cnt_eq_s < 64 ? cnt_eq_s : 64;
        for (int a = 0; a < rem; ++a) {     // smallest indices among ties
            int best = 1 << 30, bj = 0;
            for (int j = 0; j < n; ++j)
                if (eqidx[j] < best) { best = eqidx[j]; bj = j; }
            topidx[bh * U_ + cnt_gt_s + a] = best;
            eqidx[bj] = 1 << 30;
        }
    }
}

// ---------------------------------------------------------------------------
// MFMA attention partials (fp16), no-max softmax (|s| bounded ~4).
// Grid (NCHUNK=16, 32 bh), 256 thr.  Block = 512 keys, 4 chunks of 128.
// ---------------------------------------------------------------------------
__global__ __launch_bounds__(256, 2) void attn_mfma(
    const ushortT* __restrict__ Qbuf, const ushortT* __restrict__ Kbuf,
    const ushortT* __restrict__ VT, const int* __restrict__ topidx,
    float* __restrict__ pl, float* __restrict__ pacc)
{
    __shared__ float sc[48 * 132];          // scores f32; P fp16 in-place
    __shared__ ushortT Qb[48 * 72];         // Q fp16, scale folded, padded

    const int tid = threadIdx.x;
    const int w = tid >> 6, lane = tid & 63;
    const int quad = lane >> 4, c16 = lane & 15;
    const int bh = blockIdx.y;
    const int s_base = blockIdx.x * 512;

    for (int i = tid; i < 48 * 64; i += 256) {
        int q = i >> 6, d = i & 63;
        float v = 0.f;
        if (q < U_) {
            int s = topidx[bh * U_ + q];
            v = h2f(Qbuf[((size_t)bh * 8192 + s) * 64 + d]) * 0.125f;
        }
        Qb[q * 72 + d] = f2h(v);
    }

    f32x4 O[3];
#pragma unroll
    for (int mt = 0; mt < 3; ++mt) O[mt] = (f32x4){0.f, 0.f, 0.f, 0.f};
    float lacc[12];
#pragma unroll
    for (int qi = 0; qi < 12; ++qi) lacc[qi] = 0.f;

    __syncthreads();

    half8 qa[3][2];
#pragma unroll
    for (int mt = 0; mt < 3; ++mt)
#pragma unroll
        for (int kk = 0; kk < 2; ++kk)
            qa[mt][kk] = *(const half8*)&Qb[(mt * 16 + c16) * 72 + kk * 32 + quad * 8];

    const ushortT* kb  = Kbuf + (size_t)bh * 8192 * 64;
    const ushortT* vtb = VT + ((size_t)bh * 64 + w * 16 + c16) * 8192;

    for (int ci = 0; ci < 4; ++ci) {
        const int s0 = s_base + ci * 128;

        half8 kf[2][2];
#pragma unroll
        for (int nt2 = 0; nt2 < 2; ++nt2)
#pragma unroll
            for (int kk = 0; kk < 2; ++kk)
                kf[nt2][kk] = *(const half8*)&kb[
                    (size_t)(s0 + w * 32 + nt2 * 16 + c16) * 64 + kk * 32 + quad * 8];
        f32x4 sacc[3][2];
#pragma unroll
        for (int mt = 0; mt < 3; ++mt)
#pragma unroll
            for (int nt2 = 0; nt2 < 2; ++nt2) {
                sacc[mt][nt2] = (f32x4){0.f, 0.f, 0.f, 0.f};
#pragma unroll
                for (int kk = 0; kk < 2; ++kk)
                    sacc[mt][nt2] = __builtin_amdgcn_mfma_f32_16x16x32_f16(
                        qa[mt][kk], kf[nt2][kk], sacc[mt][nt2], 0, 0, 0);
            }
#pragma unroll
        for (int mt = 0; mt < 3; ++mt)
#pragma unroll
            for (int nt2 = 0; nt2 < 2; ++nt2)
#pragma unroll
                for (int r = 0; r < 4; ++r)
                    sc[(mt * 16 + quad * 4 + r) * 132 + w * 32 + nt2 * 16 + c16] =
                        sacc[mt][nt2][r];
        __syncthreads();

        half8 vb[4];
#pragma unroll
        for (int kk = 0; kk < 4; ++kk)
            vb[kk] = *(const half8*)&vtb[s0 + kk * 32 + quad * 8];

#pragma unroll
        for (int qi = 0; qi < 12; ++qi) {
            const int q = w * 12 + qi;
            float x0 = sc[q * 132 + lane];
            float x1 = sc[q * 132 + 64 + lane];
            ushortT u0 = f2h(__expf(x0));
            ushortT u1 = f2h(__expf(x1));
            lacc[qi] += h2f(u0) + h2f(u1);
            ushortT* pr = (ushortT*)&sc[q * 132];
            pr[lane] = u0;
            pr[lane + 64] = u1;
        }
        __syncthreads();

#pragma unroll
        for (int mt = 0; mt < 3; ++mt)
#pragma unroll
            for (int kk = 0; kk < 4; ++kk) {
                half8 pa = *(const half8*)((const ushortT*)sc +
                    (size_t)(mt * 16 + c16) * 264 + kk * 32 + quad * 8);
                O[mt] = __builtin_amdgcn_mfma_f32_16x16x32_f16(pa, vb[kk], O[mt], 0, 0, 0);
            }
        __syncthreads();
    }

#pragma unroll
    for (int mt = 0; mt < 3; ++mt)
#pragma unroll
        for (int r = 0; r < 4; ++r) {
            const int q = mt * 16 + quad * 4 + r;
            if (q < U_)
                pacc[(((size_t)bh * NCHUNK + blockIdx.x) * U_ + q) * 64 + w * 16 + c16] =
                    O[mt][r];
        }
#pragma unroll
    for (int qi = 0; qi < 12; ++qi) {
        const int q = w * 12 + qi;
        float ssum = lacc[qi];
#pragma unroll
        for (int off = 1; off < 64; off <<= 1) ssum += __shfl_xor(ssum, off);
        if (lane == 0 && q < U_)
            pl[((size_t)bh * NCHUNK + blockIdx.x) * U_ + q] = ssum;
    }
}

// ---------------------------------------------------------------------------
// Broadcast fill: out[b,s,:] = out_base[b,:]
// ---------------------------------------------------------------------------
__global__ __launch_bounds__(256) void fill_kernel(
    const float* __restrict__ outbase, float* __restrict__ out)
{
    size_t gid = (size_t)blockIdx.x * 256 + threadIdx.x;
    size_t e0 = gid * 4;
    int b = (int)(e0 >> 22);          // 8192*512 = 2^22
    int col = (int)(e0 & 511);
    float4 v = *(const float4*)&outbase[b * 512 + col];
    *(float4*)&out[e0] = v;
}

// ---------------------------------------------------------------------------
// Merged combine + correction: block (q, bh).
// ---------------------------------------------------------------------------
__global__ __launch_bounds__(512) void corr_out_kernel(
    const float* __restrict__ pl, const float* __restrict__ pacc,
    const float* __restrict__ vsum, const float* __restrict__ Wo,
    const int* __restrict__ topidx, float* __restrict__ out)
{
    __shared__ float corrS[64];
    const int q = blockIdx.x, bh = blockIdx.y;
    const int b = bh >> 3, h = bh & 7, tid = threadIdx.x;
    if (tid < 64) {
        float L = 0.f, a = 0.f;
        for (int c = 0; c < NCHUNK; ++c) {
            L += pl[((size_t)bh * NCHUNK + c) * U_ + q];
            a += pacc[(((size_t)bh * NCHUNK + c) * U_ + q) * 64 + tid];
        }
        corrS[tid] = a / L - vsum[b * 512 + h * 64 + tid] * (1.0f / S_);
    }
    __syncthreads();
    const int s = topidx[bh * U_ + q];
    const int d = tid;
    float delta = 0.f;
#pragma unroll
    for (int r = 0; r < 64; ++r)
        delta = fmaf(corrS[r], Wo[(size_t)(h * 64 + r) * 512 + d], delta);
    atomicAdd(&out[((size_t)b * S_ + s) * 512 + d], delta);
}

// ---------------------------------------------------------------------------
extern "C" void kernel_launch(void* const* d_in, const int* in_sizes, int n_in,
                              void* d_out, int out_size, void* d_ws, size_t ws_size,
                              hipStream_t stream)
{
    const float* X  = (const float*)d_in[0];
    const float* Wq = (const float*)d_in[1];
    const float* bq = (const float*)d_in[2];
    const float* Wk = (const float*)d_in[3];
    const float* bk = (const float*)d_in[4];
    const float* Wv = (const float*)d_in[5];
    const float* bv = (const float*)d_in[6];
    const float* Wo = (const float*)d_in[7];
    const float* bo = (const float*)d_in[8];
    float* out = (float*)d_out;

    char* ws = (char*)d_ws;
    size_t off = 0;
    auto alloc = [&](size_t bytes) {
        void* p = ws + off;
        off = (off + bytes + 255) & ~(size_t)255;
        return p;
    };
    ushortT* Xf   = (ushortT*)alloc((size_t)B_ * S_ * D_ * 2);
    ushortT* Qbuf = (ushortT*)alloc((size_t)B_ * S_ * D_ * 2);
    ushortT* Kbuf = (ushortT*)alloc((size_t)B_ * S_ * D_ * 2);
    ushortT* VT   = (ushortT*)alloc((size_t)B_ * S_ * D_ * 2);
    ushortT* WqT  = (ushortT*)alloc((size_t)D_ * D_ * 2);
    ushortT* WkT  = (ushortT*)alloc((size_t)D_ * D_ * 2);
    ushortT* WvT  = (ushortT*)alloc((size_t)D_ * D_ * 2);
    float* sparsity = (float*)alloc((size_t)B_ * H_ * S_ * 4);
    int*   topidx   = (int*)alloc((size_t)B_ * H_ * U_ * 4);
    float* pl       = (float*)alloc((size_t)B_ * H_ * NCHUNK * U_ * 4);
    float* pacc     = (float*)alloc((size_t)B_ * H_ * NCHUNK * U_ * 64 * 4);
    float* vsum     = (float*)alloc((size_t)B_ * 512 * 4);
    float* outbase  = (float*)alloc((size_t)B_ * 512 * 4);

    prep_kernel<<<8960, 256, 0, stream>>>(X, Xf, Wq, Wk, Wv, WqT, WkT, WvT,
                                          vsum, outbase);
    qkv_mfma<<<dim3(256, 6), 512, 0, stream>>>(Xf, WqT, WkT, WvT,
                                               bq, bk, bv, Qbuf, Kbuf, VT,
                                               sparsity, vsum);
    topk_kernel<<<64, 256, 0, stream>>>(sparsity, topidx, vsum, Wo, bo, outbase);
    attn_mfma<<<dim3(NCHUNK, B_ * H_), 256, 0, stream>>>(Qbuf, Kbuf, VT, topidx,
                                                         pl, pacc);
    fill_kernel<<<(B_ * S_ * D_ / 4 + 255) / 256, 256, 0, stream>>>(outbase, out);
    corr_out_kernel<<<dim3(U_, B_ * H_), 512, 0, stream>>>(pl, pacc, vsum, Wo,
                                                           topidx, out);
}